// Round 2
// baseline (173.135 us; speedup 1.0000x reference)
//
#include <hip/hip_runtime.h>

#define B      8192
#define C      2048
#define HALF   4096
#define L      6
#define NRGB   4
#define BT     (B + L)                    // 8198
#define XOUT_ELEMS ((size_t)BT * C)       // 16789504

#define BLK_A  256                        // blocks in fused kernel
#define THR_A  512                        // threads (8 waves)
#define ROWS_A (B / BLK_A)                // 32 rows per block
#define WAVES_A (THR_A / 64)              // 8
#define RPW    (ROWS_A / WAVES_A)         // 4 rows per wave

// ---------------- Kernel A: fused score + copy + per-cam weighted LDS accumulation ----
// partials layout (swizzled for LDS bank-conflict-free ds_add):
//   part[cam][k][c][ln]  (cam<6, k<8, c<4, ln<64)  == element col = (k*64+ln)*4 + c
__global__ __launch_bounds__(THR_A) void k_fused(
    const float* __restrict__ x, const int* __restrict__ cams,
    const float* __restrict__ att_w, const float* __restrict__ att_b,
    float* __restrict__ xout, float* __restrict__ partials,
    float* __restrict__ statpart) {
  __shared__ float part[L * C];           // 48 KB
  __shared__ float sstat[12];             // [0..5]=denom partial, [6..11]=count partial
  const int tid = threadIdx.x;
  const int wv  = tid >> 6;
  const int ln  = tid & 63;

  for (int i = tid; i < L * C; i += THR_A) part[i] = 0.f;
  if (tid < 12) sstat[tid] = 0.f;
  __syncthreads();

  const int r0 = blockIdx.x * ROWS_A;
  const float4* __restrict__ x4 = (const float4*)x;
  const float4* __restrict__ w4 = (const float4*)att_w;
  float4* __restrict__ o4       = (float4*)xout;

  for (int j = 0; j < RPW; ++j) {
    const int r   = r0 + wv + j * WAVES_A;          // each wave: 4 distinct rows
    const int cam = cams[r];                        // wave-uniform
    const size_t xbase = (size_t)r   * (C / 4);
    const size_t wbase = (size_t)cam * (C / 4);
    float4 xv[8];
    float  acc = 0.f;
    #pragma unroll
    for (int k = 0; k < 8; ++k) {
      const float4 xx = x4[xbase + k * 64 + ln];
      const float4 ww = w4[wbase + k * 64 + ln];
      xv[k] = xx;
      acc += xx.x * ww.x + xx.y * ww.y + xx.z * ww.z + xx.w * ww.w;
    }
    #pragma unroll
    for (int off = 32; off > 0; off >>= 1) acc += __shfl_xor(acc, off, 64);
    const float s = acc + att_b[cam];

    float* __restrict__ pc = part + cam * C;
    #pragma unroll
    for (int k = 0; k < 8; ++k) {
      o4[xbase + k * 64 + ln] = xv[k];
      // swizzled LDS accumulate: lanes hit consecutive banks per component
      atomicAdd(&pc[k * 256 + 0 * 64 + ln], xv[k].x * s);
      atomicAdd(&pc[k * 256 + 1 * 64 + ln], xv[k].y * s);
      atomicAdd(&pc[k * 256 + 2 * 64 + ln], xv[k].z * s);
      atomicAdd(&pc[k * 256 + 3 * 64 + ln], xv[k].w * s);
    }
    if (ln == 0) { atomicAdd(&sstat[cam], s); atomicAdd(&sstat[6 + cam], 1.f); }
  }
  __syncthreads();

  // write out LDS partials (keep swizzled layout; tail kernel unswizzles)
  float4* __restrict__ p4 = (float4*)(partials + (size_t)blockIdx.x * (L * C));
  const float4* __restrict__ lp4 = (const float4*)part;
  for (int i = tid; i < (L * C) / 4; i += THR_A) p4[i] = lp4[i];
  if (tid < 12) statpart[blockIdx.x * 12 + tid] = sstat[tid];
}

// ---------------- Kernel S: reduce per-block stats -> stats[18] ----------------
// stats: [0..5]=denom, [6..11]=counts, [12..17]=Dc (cam-node rsqrt degree)
__global__ __launch_bounds__(256) void k_stats2(
    const float* __restrict__ statpart, float* __restrict__ stats) {
  const int tid = threadIdx.x;
  float loc[12];
  #pragma unroll
  for (int i = 0; i < 12; ++i) loc[i] = 0.f;
  for (int g = tid; g < BLK_A; g += 256) {
    #pragma unroll
    for (int i = 0; i < 12; ++i) loc[i] += statpart[g * 12 + i];
  }
  #pragma unroll
  for (int off = 32; off > 0; off >>= 1) {
    #pragma unroll
    for (int i = 0; i < 12; ++i) loc[i] += __shfl_xor(loc[i], off, 64);
  }
  __shared__ float sd[4][12];
  if ((tid & 63) == 0) {
    #pragma unroll
    for (int i = 0; i < 12; ++i) sd[tid >> 6][i] = loc[i];
  }
  __syncthreads();
  if (tid < 12) stats[tid] = sd[0][tid] + sd[1][tid] + sd[2][tid] + sd[3][tid];
  if (tid == 0) {
    const float nr = sd[0][6] + sd[1][6] + sd[2][6] + sd[3][6]
                   + sd[0][7] + sd[1][7] + sd[2][7] + sd[3][7]
                   + sd[0][8] + sd[1][8] + sd[2][8] + sd[3][8]
                   + sd[0][9] + sd[1][9] + sd[2][9] + sd[3][9];
    const float ni = sd[0][10] + sd[1][10] + sd[2][10] + sd[3][10]
                   + sd[0][11] + sd[1][11] + sd[2][11] + sd[3][11];
    #pragma unroll
    for (int l = 0; l < L; ++l)
      stats[12 + l] = rsqrtf(((l < NRGB) ? ni : nr) + 1.0f);
  }
}

// ---------------- Kernel T: reduce partials -> tail rows of x_out ----------------
__global__ __launch_bounds__(256) void k_tail2(
    const float* __restrict__ partials, const float* __restrict__ stats,
    const float* __restrict__ running_mean, float* __restrict__ xout) {
  const int l     = blockIdx.y;                       // [0, 6)
  const int c4    = blockIdx.x * 64 + (threadIdx.x & 63);   // [0, 512)
  const int chunk = threadIdx.x >> 6;                 // [0, 4)
  const int k     = c4 >> 6;                          // swizzle coords
  const int lnp   = c4 & 63;
  const size_t eb = (size_t)l * C + k * 256 + lnp;    // + c*64 within

  float4 s = {0.f, 0.f, 0.f, 0.f};
  for (int g = chunk * (BLK_A / 4); g < (chunk + 1) * (BLK_A / 4); ++g) {
    const float* __restrict__ pg = partials + (size_t)g * (L * C) + eb;
    s.x += pg[0 * 64]; s.y += pg[1 * 64]; s.z += pg[2 * 64]; s.w += pg[3 * 64];
  }
  __shared__ float4 red[4][64];
  red[chunk][lnp] = s;
  __syncthreads();
  if (threadIdx.x < 64) {
    const float4 a = red[0][lnp], b = red[1][lnp], c = red[2][lnp], d = red[3][lnp];
    float4 t;
    t.x = a.x + b.x + c.x + d.x;  t.y = a.y + b.y + c.y + d.y;
    t.z = a.z + b.z + c.z + d.z;  t.w = a.w + b.w + c.w + d.w;
    const float denom = stats[l];
    const float cnt   = stats[6 + l];
    float4 o;
    if (cnt > 0.0f) {
      const float inv = 1.0f / denom;
      o.x = t.x * inv; o.y = t.y * inv; o.z = t.z * inv; o.w = t.w * inv;
    } else {
      o = ((const float4*)running_mean)[(size_t)l * (C / 4) + c4];
    }
    ((float4*)xout)[((size_t)B + l) * (C / 4) + c4] = o;
  }
}

// ---------------- Kernel ADJ: write adjacency (unchanged, verified) ----------------
__global__ __launch_bounds__(256) void k_adj(
    const int* __restrict__ cams, const float* __restrict__ stats,
    float* __restrict__ adj) {
  const int i   = blockIdx.x;
  const int tid = threadIdx.x;
  const float ds_rgb = rsqrtf((float)HALF + 2.0f);   // 1/sqrt(4098)
  const float ds_ir  = rsqrtf((float)HALF + 4.0f);   // 1/sqrt(4100)
  float2* __restrict__ row = (float2*)(adj + (size_t)i * BT);
  const int2* __restrict__ cams2 = (const int2*)cams;

  if (i < B) {
    const int   ci    = cams[i];
    const float Di    = (ci < NRGB) ? ds_rgb : ds_ir;
    const bool half_i = (i < HALF);
    for (int k = tid; k < HALF; k += 256) {
      const bool same = ((k < HALF / 2) == half_i);
      const int2 c = cams2[k];
      float2 v;
      v.x = same ? Di * ((c.x < NRGB) ? ds_rgb : ds_ir) : 0.0f;
      v.y = same ? Di * ((c.y < NRGB) ? ds_rgb : ds_ir) : 0.0f;
      row[k] = v;
    }
    if (tid < 3) {
      const int k  = HALF + tid;
      const int l0 = 2 * tid;
      const bool rgb_i = (ci < NRGB);
      float2 v;
      v.x = (rgb_i != (l0     < NRGB)) ? Di * stats[12 + l0]     : 0.0f;
      v.y = (rgb_i != ((l0+1) < NRGB)) ? Di * stats[12 + l0 + 1] : 0.0f;
      row[k] = v;
    }
  } else {
    const int   l     = i - B;
    const float Dcl   = stats[12 + l];
    const bool  rgb_l = (l < NRGB);
    for (int k = tid; k < HALF; k += 256) {
      const int2 c = cams2[k];
      float2 v;
      v.x = ((c.x < NRGB) != rgb_l) ? Dcl * ((c.x < NRGB) ? ds_rgb : ds_ir) : 0.0f;
      v.y = ((c.y < NRGB) != rgb_l) ? Dcl * ((c.y < NRGB) ? ds_rgb : ds_ir) : 0.0f;
      row[k] = v;
    }
    if (tid < 3) {
      const int k  = HALF + tid;
      const int l0 = 2 * tid;
      float2 v;
      v.x = (l0     == l) ? Dcl * Dcl : 0.0f;
      v.y = (l0 + 1 == l) ? Dcl * Dcl : 0.0f;
      row[k] = v;
    }
  }
}

extern "C" void kernel_launch(void* const* d_in, const int* in_sizes, int n_in,
                              void* d_out, int out_size, void* d_ws, size_t ws_size,
                              hipStream_t stream) {
  const float* x            = (const float*)d_in[0];
  const int*   cams         = (const int*)d_in[1];
  const float* att_w        = (const float*)d_in[4];
  const float* att_b        = (const float*)d_in[5];
  const float* running_mean = (const float*)d_in[6];

  float* xout = (float*)d_out;
  float* adj  = xout + XOUT_ELEMS;

  // Scratch consumed strictly BEFORE k_adj lives inside the adj output region
  // (k_adj overwrites all of it afterwards, stream-ordered).
  float* partials = adj;                                  // BLK_A*L*C floats (12.6 MB)
  float* statpart = adj + (size_t)BLK_A * L * C;          // BLK_A*12 floats
  // stats is read BY k_adj -> lives in d_ws (72 B).
  float* stats    = (float*)d_ws;

  k_fused <<<BLK_A, THR_A,    0, stream>>>(x, cams, att_w, att_b, xout, partials, statpart);
  k_stats2<<<1, 256,          0, stream>>>(statpart, stats);
  k_tail2 <<<dim3(8, L), 256, 0, stream>>>(partials, stats, running_mean, xout);
  k_adj   <<<BT, 256,         0, stream>>>(cams, stats, adj);
}

// Round 3
// 109.748 us; speedup vs baseline: 1.5776x; 1.5776x over previous
//
#include <hip/hip_runtime.h>

#define B      8192
#define C      2048
#define C4     (C / 4)                    // 512
#define HALF   4096
#define L      6
#define NRGB   4
#define BT     (B + L)                    // 8198
#define XOUT_ELEMS ((size_t)BT * C)       // 16789504

#define NBLK   512                        // blocks in fused kernel
#define RPB    16                         // rows per block (8192/512)

// ---------------- Kernel 1: fused score + copy + per-cam register accumulation ------
// partials[g][cam][col4]  (g<512, cam<6, col4<512) float4 entries
__global__ __launch_bounds__(256) void k_fused(
    const float* __restrict__ x, const int* __restrict__ cams,
    const float* __restrict__ att_w, const float* __restrict__ att_b,
    float* __restrict__ xout, float* __restrict__ partials,
    float* __restrict__ gdenom, int* __restrict__ gcount) {
  __shared__ float ls[RPB];
  __shared__ int   lcam[RPB];
  __shared__ float sden[L];
  __shared__ int   scnt[L];
  const int tid = threadIdx.x;
  const int wv  = tid >> 6;
  const int ln  = tid & 63;
  const int r0  = blockIdx.x * RPB;

  if (tid < L)   { sden[tid] = 0.f; scnt[tid] = 0; }
  if (tid < RPB) lcam[tid] = cams[r0 + tid];
  __syncthreads();

  const float4* __restrict__ x4 = (const float4*)x;
  const float4* __restrict__ w4 = (const float4*)att_w;
  float4* __restrict__ o4       = (float4*)xout;

  // ---- phase A: scores (each of 4 waves handles 4 rows) ----
  for (int j = 0; j < 4; ++j) {
    const int rl  = wv * 4 + j;
    const int cam = lcam[rl];
    const size_t xb = (size_t)(r0 + rl) * C4;
    const size_t wb = (size_t)cam * C4;
    float acc = 0.f;
    #pragma unroll
    for (int k = 0; k < 8; ++k) {
      const float4 xx = x4[xb + k * 64 + ln];
      const float4 ww = w4[wb + k * 64 + ln];
      acc += xx.x * ww.x + xx.y * ww.y + xx.z * ww.z + xx.w * ww.w;
    }
    #pragma unroll
    for (int off = 32; off > 0; off >>= 1) acc += __shfl_xor(acc, off, 64);
    if (ln == 0) {
      const float s = acc + att_b[cam];
      ls[rl] = s;
      atomicAdd(&sden[cam], s);
      atomicAdd(&scnt[cam], 1);
    }
  }
  __syncthreads();

  // ---- phase B: copy + weighted per-cam column sums in registers ----
  float4 a[L][2];
  #pragma unroll
  for (int l = 0; l < L; ++l) {
    a[l][0] = make_float4(0.f, 0.f, 0.f, 0.f);
    a[l][1] = make_float4(0.f, 0.f, 0.f, 0.f);
  }
  for (int rl = 0; rl < RPB; ++rl) {
    const int   cam = __builtin_amdgcn_readfirstlane(lcam[rl]);
    const float s   = ls[rl];
    const size_t xb = (size_t)(r0 + rl) * C4;
    const float4 xa = x4[xb + tid];
    const float4 xc = x4[xb + 256 + tid];
    o4[xb + tid]       = xa;
    o4[xb + 256 + tid] = xc;
    float4 va, vc;
    va.x = xa.x * s; va.y = xa.y * s; va.z = xa.z * s; va.w = xa.w * s;
    vc.x = xc.x * s; vc.y = xc.y * s; vc.z = xc.z * s; vc.w = xc.w * s;
    #define ACC(l) { a[l][0].x+=va.x; a[l][0].y+=va.y; a[l][0].z+=va.z; a[l][0].w+=va.w; \
                     a[l][1].x+=vc.x; a[l][1].y+=vc.y; a[l][1].z+=vc.z; a[l][1].w+=vc.w; }
    if      (cam == 0) ACC(0)
    else if (cam == 1) ACC(1)
    else if (cam == 2) ACC(2)
    else if (cam == 3) ACC(3)
    else if (cam == 4) ACC(4)
    else               ACC(5)
    #undef ACC
  }
  float4* __restrict__ p4 = (float4*)partials + (size_t)blockIdx.x * (L * C4);
  #pragma unroll
  for (int l = 0; l < L; ++l) {
    p4[l * C4 + tid]       = a[l][0];
    p4[l * C4 + 256 + tid] = a[l][1];
  }
  if (tid < L) {
    atomicAdd(&gdenom[tid], sden[tid]);
    atomicAdd(&gcount[tid], scnt[tid]);
  }
}

// ---------------- Kernel 2: reduce partials -> tail rows of x_out ----------------
__global__ __launch_bounds__(256) void k_tail(
    const float* __restrict__ partials, const float* __restrict__ gdenom,
    const int* __restrict__ gcount, const float* __restrict__ running_mean,
    float* __restrict__ xout) {
  const int l    = blockIdx.y;                       // [0, 6)
  const int c4i  = threadIdx.x & 15;
  const int gs   = threadIdx.x >> 4;                 // [0, 16)
  const int col4 = blockIdx.x * 16 + c4i;            // [0, 512)
  const float4* __restrict__ p4 = (const float4*)partials;

  float4 acc = make_float4(0.f, 0.f, 0.f, 0.f);
  for (int t = 0; t < NBLK / 16; ++t) {              // 32 groups per thread
    const int g = gs + t * 16;
    const float4 v = p4[((size_t)g * L + l) * C4 + col4];
    acc.x += v.x; acc.y += v.y; acc.z += v.z; acc.w += v.w;
  }
  __shared__ float4 red[16][16];
  red[gs][c4i] = acc;
  __syncthreads();
  if (threadIdx.x < 16) {
    const int myc4 = blockIdx.x * 16 + threadIdx.x;
    float4 t = make_float4(0.f, 0.f, 0.f, 0.f);
    #pragma unroll
    for (int g = 0; g < 16; ++g) {
      const float4 v = red[g][threadIdx.x];
      t.x += v.x; t.y += v.y; t.z += v.z; t.w += v.w;
    }
    float4 o;
    if (gcount[l] > 0) {
      const float inv = 1.0f / gdenom[l];
      o.x = t.x * inv; o.y = t.y * inv; o.z = t.z * inv; o.w = t.w * inv;
    } else {
      o = ((const float4*)running_mean)[(size_t)l * C4 + myc4];
    }
    ((float4*)xout)[((size_t)B + l) * C4 + myc4] = o;
  }
}

// ---------------- Kernel 3: write adjacency ----------------
// Cam-node degree is 4096+1 by construction (halves are strictly RGB / strictly IR),
// so Dc = rsqrt(4097) is a constant; k_adj depends only on cams.
__global__ __launch_bounds__(256) void k_adj(
    const int* __restrict__ cams, float* __restrict__ adj) {
  const int i   = blockIdx.x;
  const int tid = threadIdx.x;
  const float ds_rgb = rsqrtf((float)HALF + 2.0f);   // 1/sqrt(4098)
  const float ds_ir  = rsqrtf((float)HALF + 4.0f);   // 1/sqrt(4100)
  const float dc     = rsqrtf((float)HALF + 1.0f);   // 1/sqrt(4097)
  float2* __restrict__ row = (float2*)(adj + (size_t)i * BT);
  const int2* __restrict__ cams2 = (const int2*)cams;

  if (i < B) {
    const int   ci    = cams[i];
    const float Di    = (ci < NRGB) ? ds_rgb : ds_ir;
    const bool half_i = (i < HALF);
    for (int k = tid; k < HALF; k += 256) {
      const bool same = ((k < HALF / 2) == half_i);
      const int2 c = cams2[k];
      float2 v;
      v.x = same ? Di * ((c.x < NRGB) ? ds_rgb : ds_ir) : 0.0f;
      v.y = same ? Di * ((c.y < NRGB) ? ds_rgb : ds_ir) : 0.0f;
      row[k] = v;
    }
    if (tid < 3) {
      const int k  = HALF + tid;
      const int l0 = 2 * tid;
      const bool rgb_i = (ci < NRGB);
      float2 v;
      v.x = (rgb_i != (l0     < NRGB)) ? Di * dc : 0.0f;
      v.y = (rgb_i != ((l0+1) < NRGB)) ? Di * dc : 0.0f;
      row[k] = v;
    }
  } else {
    const int  l     = i - B;
    const bool rgb_l = (l < NRGB);
    for (int k = tid; k < HALF; k += 256) {
      const int2 c = cams2[k];
      float2 v;
      v.x = ((c.x < NRGB) != rgb_l) ? dc * ((c.x < NRGB) ? ds_rgb : ds_ir) : 0.0f;
      v.y = ((c.y < NRGB) != rgb_l) ? dc * ((c.y < NRGB) ? ds_rgb : ds_ir) : 0.0f;
      row[k] = v;
    }
    if (tid < 3) {
      const int k  = HALF + tid;
      const int l0 = 2 * tid;
      float2 v;
      v.x = (l0     == l) ? dc * dc : 0.0f;
      v.y = (l0 + 1 == l) ? dc * dc : 0.0f;
      row[k] = v;
    }
  }
}

extern "C" void kernel_launch(void* const* d_in, const int* in_sizes, int n_in,
                              void* d_out, int out_size, void* d_ws, size_t ws_size,
                              hipStream_t stream) {
  const float* x            = (const float*)d_in[0];
  const int*   cams         = (const int*)d_in[1];
  const float* att_w        = (const float*)d_in[4];
  const float* att_b        = (const float*)d_in[5];
  const float* running_mean = (const float*)d_in[6];

  float* xout = (float*)d_out;
  float* adj  = xout + XOUT_ELEMS;

  // partials (25 MB) live at the start of the adj region: consumed by k_tail
  // strictly before k_adj overwrites them (stream-ordered).
  float* partials = adj;
  // 48-byte accumulator block in d_ws, zeroed every call (graph-capturable).
  float* gdenom = (float*)d_ws;            // 6 floats
  int*   gcount = (int*)d_ws + 6;          // 6 ints

  hipMemsetAsync(d_ws, 0, 12 * sizeof(float), stream);
  k_fused<<<NBLK, 256,        0, stream>>>(x, cams, att_w, att_b, xout, partials,
                                           gdenom, gcount);
  k_tail <<<dim3(32, L), 256, 0, stream>>>(partials, gdenom, gcount, running_mean, xout);
  k_adj  <<<BT, 256,          0, stream>>>(cams, adj);
}

// Round 4
// 109.692 us; speedup vs baseline: 1.5784x; 1.0005x over previous
//
#include <hip/hip_runtime.h>

#define B      8192
#define C      2048
#define C4     (C / 4)                    // 512
#define HALF   4096
#define L      6
#define NRGB   4
#define BT     (B + L)                    // 8198
#define XOUT_ELEMS ((size_t)BT * C)       // 16789504

#define NBLK   256                        // fused blocks
#define RPB    32                         // rows per fused block (8192/256)
#define SKIP   512                        // adj rows reserved for partials scratch
// partials bytes = NBLK*L*C*4 = 12,582,912 ; statpart = NBLK*12*4 = 12,288
// region available = SKIP rows * BT*4 = 16,789,504 B  -> fits.

// ---------------- shared device helper: write one adjacency row ----------------
__device__ __forceinline__ void write_adj_row(
    const int i, const int tid,
    const int* __restrict__ cams, float* __restrict__ adj) {
  const float ds_rgb = rsqrtf((float)HALF + 2.0f);   // 1/sqrt(4098)
  const float ds_ir  = rsqrtf((float)HALF + 4.0f);   // 1/sqrt(4100)
  const float dc     = rsqrtf((float)HALF + 1.0f);   // 1/sqrt(4097): cam degree fixed by construction
  float2* __restrict__ row = (float2*)(adj + (size_t)i * BT);
  const int2* __restrict__ cams2 = (const int2*)cams;

  if (i < B) {
    const int   ci    = cams[i];
    const float Di    = (ci < NRGB) ? ds_rgb : ds_ir;
    const bool half_i = (i < HALF);
    for (int k = tid; k < HALF; k += 256) {
      const bool same = ((k < HALF / 2) == half_i);
      const int2 c = cams2[k];
      float2 v;
      v.x = same ? Di * ((c.x < NRGB) ? ds_rgb : ds_ir) : 0.0f;
      v.y = same ? Di * ((c.y < NRGB) ? ds_rgb : ds_ir) : 0.0f;
      row[k] = v;
    }
    if (tid < 3) {
      const int k  = HALF + tid;
      const int l0 = 2 * tid;
      const bool rgb_i = (ci < NRGB);
      float2 v;
      v.x = (rgb_i != (l0     < NRGB)) ? Di * dc : 0.0f;
      v.y = (rgb_i != ((l0+1) < NRGB)) ? Di * dc : 0.0f;
      row[k] = v;
    }
  } else {
    const int  l     = i - B;
    const bool rgb_l = (l < NRGB);
    for (int k = tid; k < HALF; k += 256) {
      const int2 c = cams2[k];
      float2 v;
      v.x = ((c.x < NRGB) != rgb_l) ? dc * ((c.x < NRGB) ? ds_rgb : ds_ir) : 0.0f;
      v.y = ((c.y < NRGB) != rgb_l) ? dc * ((c.y < NRGB) ? ds_rgb : ds_ir) : 0.0f;
      row[k] = v;
    }
    if (tid < 3) {
      const int k  = HALF + tid;
      const int l0 = 2 * tid;
      float2 v;
      v.x = (l0     == l) ? dc * dc : 0.0f;
      v.y = (l0 + 1 == l) ? dc * dc : 0.0f;
      row[k] = v;
    }
  }
}

// ---------------- Kernel 1: fused (blocks 0..NBLK-1) + adj rows SKIP.. (rest) ------
__global__ __launch_bounds__(256) void k_main(
    const float* __restrict__ x, const int* __restrict__ cams,
    const float* __restrict__ att_w, const float* __restrict__ att_b,
    float* __restrict__ xout, float* __restrict__ partials,
    float* __restrict__ statpart, float* __restrict__ adj) {
  const int bx  = blockIdx.x;
  const int tid = threadIdx.x;

  if (bx >= NBLK) {                       // ---- adjacency stream: rows SKIP..BT-1 ----
    write_adj_row(bx - NBLK + SKIP, tid, cams, adj);
    return;
  }

  // ---- fused path ----
  __shared__ float ls[RPB];
  __shared__ int   lcam[RPB];
  __shared__ float sden[L];
  __shared__ int   scnt[L];
  const int wv = tid >> 6;
  const int ln = tid & 63;
  const int r0 = bx * RPB;

  if (tid < L)   { sden[tid] = 0.f; scnt[tid] = 0; }
  if (tid < RPB) lcam[tid] = cams[r0 + tid];
  __syncthreads();

  const float4* __restrict__ x4 = (const float4*)x;
  const float4* __restrict__ w4 = (const float4*)att_w;
  float4* __restrict__ o4       = (float4*)xout;

  // phase A: scores (each of 4 waves handles 8 rows)
  for (int j = 0; j < 8; ++j) {
    const int rl  = wv * 8 + j;
    const int cam = lcam[rl];
    const size_t xb = (size_t)(r0 + rl) * C4;
    const size_t wb = (size_t)cam * C4;
    float acc = 0.f;
    #pragma unroll
    for (int k = 0; k < 8; ++k) {
      const float4 xx = x4[xb + k * 64 + ln];
      const float4 ww = w4[wb + k * 64 + ln];
      acc += xx.x * ww.x + xx.y * ww.y + xx.z * ww.z + xx.w * ww.w;
    }
    #pragma unroll
    for (int off = 32; off > 0; off >>= 1) acc += __shfl_xor(acc, off, 64);
    if (ln == 0) {
      const float s = acc + att_b[cam];
      ls[rl] = s;
      atomicAdd(&sden[cam], s);
      atomicAdd(&scnt[cam], 1);
    }
  }
  __syncthreads();

  // phase B: copy + weighted per-cam column sums in registers (L2/L3-hot re-read)
  float4 a[L][2];
  #pragma unroll
  for (int l = 0; l < L; ++l) {
    a[l][0] = make_float4(0.f, 0.f, 0.f, 0.f);
    a[l][1] = make_float4(0.f, 0.f, 0.f, 0.f);
  }
  for (int rl = 0; rl < RPB; ++rl) {
    const int   cam = __builtin_amdgcn_readfirstlane(lcam[rl]);
    const float s   = ls[rl];
    const size_t xb = (size_t)(r0 + rl) * C4;
    const float4 xa = x4[xb + tid];
    const float4 xc = x4[xb + 256 + tid];
    o4[xb + tid]       = xa;
    o4[xb + 256 + tid] = xc;
    float4 va, vc;
    va.x = xa.x * s; va.y = xa.y * s; va.z = xa.z * s; va.w = xa.w * s;
    vc.x = xc.x * s; vc.y = xc.y * s; vc.z = xc.z * s; vc.w = xc.w * s;
    #define ACC(l) { a[l][0].x+=va.x; a[l][0].y+=va.y; a[l][0].z+=va.z; a[l][0].w+=va.w; \
                     a[l][1].x+=vc.x; a[l][1].y+=vc.y; a[l][1].z+=vc.z; a[l][1].w+=vc.w; }
    if      (cam == 0) ACC(0)
    else if (cam == 1) ACC(1)
    else if (cam == 2) ACC(2)
    else if (cam == 3) ACC(3)
    else if (cam == 4) ACC(4)
    else               ACC(5)
    #undef ACC
  }
  float4* __restrict__ p4 = (float4*)partials + (size_t)bx * (L * C4);
  #pragma unroll
  for (int l = 0; l < L; ++l) {
    p4[l * C4 + tid]       = a[l][0];
    p4[l * C4 + 256 + tid] = a[l][1];
  }
  if (tid < L)           statpart[bx * 12 + tid]     = sden[tid];
  else if (tid < 2 * L)  statpart[bx * 12 + tid]     = (float)scnt[tid - L];
}

// ---------------- Kernel 2: reduce partials + stats -> tail rows of x_out ----------
__global__ __launch_bounds__(256) void k_tail(
    const float* __restrict__ partials, const float* __restrict__ statpart,
    const float* __restrict__ running_mean, float* __restrict__ xout) {
  const int l    = blockIdx.x / 32;                  // [0, 6)
  const int cg   = blockIdx.x % 32;
  const int tid  = threadIdx.x;
  const int wv   = tid >> 6;
  const int ln   = tid & 63;

  // block-wide denom / count reduce from per-block stat partials (256 groups)
  float d = statpart[tid * 12 + l];
  float n = statpart[tid * 12 + 6 + l];
  #pragma unroll
  for (int off = 32; off > 0; off >>= 1) {
    d += __shfl_xor(d, off, 64);
    n += __shfl_xor(n, off, 64);
  }
  __shared__ float sdn[8];
  if (ln == 0) { sdn[wv] = d; sdn[4 + wv] = n; }

  const int c4i  = tid & 15;
  const int gs   = tid >> 4;                         // [0, 16)
  const int col4 = cg * 16 + c4i;                    // [0, 512)
  const float4* __restrict__ p4 = (const float4*)partials;
  float4 acc = make_float4(0.f, 0.f, 0.f, 0.f);
  for (int t = 0; t < NBLK / 16; ++t) {
    const int g = gs + t * 16;
    const float4 v = p4[((size_t)g * L + l) * C4 + col4];
    acc.x += v.x; acc.y += v.y; acc.z += v.z; acc.w += v.w;
  }
  __shared__ float4 red[16][16];
  red[gs][c4i] = acc;
  __syncthreads();
  if (tid < 16) {
    const float denom = sdn[0] + sdn[1] + sdn[2] + sdn[3];
    const float count = sdn[4] + sdn[5] + sdn[6] + sdn[7];
    const int myc4 = cg * 16 + tid;
    float4 t = make_float4(0.f, 0.f, 0.f, 0.f);
    #pragma unroll
    for (int g = 0; g < 16; ++g) {
      const float4 v = red[g][tid];
      t.x += v.x; t.y += v.y; t.z += v.z; t.w += v.w;
    }
    float4 o;
    if (count > 0.f) {
      const float inv = 1.0f / denom;
      o.x = t.x * inv; o.y = t.y * inv; o.z = t.z * inv; o.w = t.w * inv;
    } else {
      o = ((const float4*)running_mean)[(size_t)l * C4 + myc4];
    }
    ((float4*)xout)[((size_t)B + l) * C4 + myc4] = o;
  }
}

// ---------------- Kernel 3: adjacency rows 0..SKIP-1 (overwrites partials region) ----
__global__ __launch_bounds__(256) void k_adj_head(
    const int* __restrict__ cams, float* __restrict__ adj) {
  write_adj_row(blockIdx.x, threadIdx.x, cams, adj);
}

extern "C" void kernel_launch(void* const* d_in, const int* in_sizes, int n_in,
                              void* d_out, int out_size, void* d_ws, size_t ws_size,
                              hipStream_t stream) {
  const float* x            = (const float*)d_in[0];
  const int*   cams         = (const int*)d_in[1];
  const float* att_w        = (const float*)d_in[4];
  const float* att_b        = (const float*)d_in[5];
  const float* running_mean = (const float*)d_in[6];

  float* xout = (float*)d_out;
  float* adj  = xout + XOUT_ELEMS;

  // Scratch lives in adj rows [0, SKIP): K1's adj blocks only write rows >= SKIP,
  // K2 consumes the scratch, K3 finally overwrites rows [0, SKIP). Stream-ordered.
  float* partials = adj;                              // NBLK*L*C floats (12.6 MB)
  float* statpart = adj + (size_t)NBLK * L * C;       // NBLK*12 floats

  k_main    <<<NBLK + (BT - SKIP), 256, 0, stream>>>(x, cams, att_w, att_b, xout,
                                                     partials, statpart, adj);
  k_tail    <<<32 * L, 256, 0, stream>>>(partials, statpart, running_mean, xout);
  k_adj_head<<<SKIP,   256, 0, stream>>>(cams, adj);
}